// Round 7
// baseline (57.977 us; speedup 1.0000x reference)
//
#include <hip/hip_runtime.h>
#include <math.h>

#define HS    200   // HIST_SIZE
#define DIMV  64    // DIM
#define HID   32    // HIDDEN
#define NTH   512

typedef __attribute__((ext_vector_type(8))) short short8;   // 8 bf16 (4 VGPRs)
typedef __attribute__((ext_vector_type(4))) float f32x4;    // MFMA acc
typedef __bf16 bf2_t __attribute__((ext_vector_type(2)));
typedef float  f2_t  __attribute__((ext_vector_type(2)));

// packed f32x2 -> bf16x2 (RNE) -> v_cvt_pk_bf16_f32
__device__ __forceinline__ unsigned cvt2(float x, float y) {
    f2_t f = {x, y};
    bf2_t bv = __builtin_convertvector(f, bf2_t);
    union { bf2_t b; unsigned u; } un;
    un.b = bv;
    return un.u;
}

// DPP cross-lane (VALU pipe, no lgkmcnt)
template<int CTRL>
__device__ __forceinline__ float dpp_add(float x) {
    int y = __builtin_amdgcn_update_dpp(0, __float_as_int(x), CTRL, 0xF, 0xF, true);
    return x + __int_as_float(y);
}
template<int CTRL>
__device__ __forceinline__ float dpp_max(float x) {
    int y = __builtin_amdgcn_update_dpp(0, __float_as_int(x), CTRL, 0xF, 0xF, true);
    return fmaxf(x, __int_as_float(y));
}
#define ROR1  0x121
#define ROR2  0x122
#define ROR4  0x124
#define ROR8  0x128
#define QXOR1 0xB1   // quad_perm [1,0,3,2]
#define QXOR2 0x4E   // quad_perm [2,3,0,1]
#define HMIRR 0x141  // row_half_mirror
__device__ __forceinline__ float swz_xor16(float x) {  // lane ^ 16 (within 32)
    return __int_as_float(__builtin_amdgcn_ds_swizzle(__float_as_int(x), 0x401F));
}

// s_Mt: 32 rows (h) x 64 ushort (f), 16-B groups XOR-swizzled by (h&7).

__global__ __launch_bounds__(NTH, 8) void din_attn_kernel(
    const float* __restrict__ cand,   // B x 64
    const float* __restrict__ hist,   // B x 200 x 64
    const int*   __restrict__ lens,   // B
    const float* __restrict__ W1,     // 256 x 32
    const float* __restrict__ B1,     // 32
    const float* __restrict__ W2,     // 32
    const float* __restrict__ B2,     // 1
    float* __restrict__ out)          // B x 64
{
    __shared__ __align__(16) unsigned short s_Mt[HID * 64];  // 4096 B
    __shared__ float s_sc[208];         // 832 B (P1 writes rows 200..207, unread)
    __shared__ float s_c[HID];          // 128 B
    __shared__ float s_w2[HID];         // 128 B
    __shared__ float s_red[16];         // 64 B
    __shared__ float s_part[NTH];       // 2048 B  -> ~7.3 KB total

    const int b    = blockIdx.x;
    const int tid  = threadIdx.x;
    const int lane = tid & 63, wid = tid >> 6;
    const float* cb = cand + (size_t)b * DIMV;
    const float* hb = hist + (size_t)b * (HS * DIMV);

    // ---------------- Phase A: Mt (waves 0-3) and c (waves 4-7) -----------------
    if (tid < 256) {   // Mt[h][f] = bf16(Wb - Wd + cand[f]*Wc), one b128/thread
        const int h = tid & 31, fg = tid >> 5;     // f = fg*8..fg*8+7
        float4 cA = *(const float4*)(cb + fg * 8);
        float4 cB = *(const float4*)(cb + fg * 8 + 4);
        float cf[8] = {cA.x, cA.y, cA.z, cA.w, cB.x, cB.y, cB.z, cB.w};
        float m[8];
        #pragma unroll
        for (int ff = 0; ff < 8; ++ff) {
            int f = fg * 8 + ff;
            m[ff] = W1[(DIMV + f) * HID + h]
                  - W1[(3 * DIMV + f) * HID + h]
                  + cf[ff] * W1[(2 * DIMV + f) * HID + h];
        }
        uint4 mw = make_uint4(cvt2(m[0], m[1]), cvt2(m[2], m[3]),
                              cvt2(m[4], m[5]), cvt2(m[6], m[7]));
        int pg = fg ^ (h & 7);
        *(uint4*)&s_Mt[h * 64 + pg * 8] = mw;
        if (tid < HID) s_w2[tid] = W2[tid];
    } else {           // c[h] = sum_f cand[f]*(Wa+Wd)[f][h] + B1[h], 8-way split
        const int t2 = tid - 256;
        const int h = t2 >> 3, fg = t2 & 7;
        float p = 0.f;
        #pragma unroll
        for (int ff = 0; ff < 8; ++ff) {
            int f = fg * 8 + ff;
            p += cb[f] * (W1[f * HID + h] + W1[(3 * DIMV + f) * HID + h]);
        }
        p = dpp_add<QXOR1>(p);
        p = dpp_add<QXOR2>(p);
        p = dpp_add<HMIRR>(p);
        if ((tid & 7) == 0) s_c[h] = p + B1[h];
    }
    __syncthreads();

    // ---------------- P1: scores via MFMA, A-fragments straight from global -----
    {
        const int lc = lane & 15, lg = lane >> 4;
        const float c0  = s_c[lc],  c1  = s_c[16 + lc];
        const float w20 = s_w2[lc], w21 = s_w2[16 + lc];
        const float b2  = B2[0];

        short8 b00 = *(const short8*)&s_Mt[lc * 64        + ((lg)     ^ (lc & 7)) * 8];
        short8 b01 = *(const short8*)&s_Mt[lc * 64        + ((4 + lg) ^ (lc & 7)) * 8];
        short8 b10 = *(const short8*)&s_Mt[(16 + lc) * 64 + ((lg)     ^ (lc & 7)) * 8];
        short8 b11 = *(const short8*)&s_Mt[(16 + lc) * 64 + ((4 + lg) ^ (lc & 7)) * 8];

        for (int rt = wid; rt < 13; rt += 8) {     // wave-uniform trip count
            int s = rt * 16 + lc;
            s = (s < HS) ? s : (HS - 1);           // clamp: avoid OOB on last block
            const float* ap = hb + s * 64 + lg * 8;
            float4 A00 = *(const float4*)ap;
            float4 A01 = *(const float4*)(ap + 4);
            float4 A10 = *(const float4*)(ap + 32);
            float4 A11 = *(const float4*)(ap + 36);
            union { uint4 u; short8 s8; } ua0, ua1;
            ua0.u = make_uint4(cvt2(A00.x, A00.y), cvt2(A00.z, A00.w),
                               cvt2(A01.x, A01.y), cvt2(A01.z, A01.w));
            ua1.u = make_uint4(cvt2(A10.x, A10.y), cvt2(A10.z, A10.w),
                               cvt2(A11.x, A11.y), cvt2(A11.z, A11.w));
            f32x4 acc0 = {c0, c0, c0, c0};         // fold +c into the accumulator
            acc0 = __builtin_amdgcn_mfma_f32_16x16x32_bf16(ua0.s8, b00, acc0, 0, 0, 0);
            acc0 = __builtin_amdgcn_mfma_f32_16x16x32_bf16(ua1.s8, b01, acc0, 0, 0, 0);
            f32x4 acc1 = {c1, c1, c1, c1};
            acc1 = __builtin_amdgcn_mfma_f32_16x16x32_bf16(ua0.s8, b10, acc1, 0, 0, 0);
            acc1 = __builtin_amdgcn_mfma_f32_16x16x32_bf16(ua1.s8, b11, acc1, 0, 0, 0);
            float p[4];
            #pragma unroll
            for (int r = 0; r < 4; ++r)
                p[r] = fmaxf(acc0[r], 0.f) * w20 + fmaxf(acc1[r], 0.f) * w21;
            #pragma unroll
            for (int r = 0; r < 4; ++r) {          // 16-lane rotate-reduce, VALU pipe
                p[r] = dpp_add<ROR1>(p[r]);
                p[r] = dpp_add<ROR2>(p[r]);
                p[r] = dpp_add<ROR4>(p[r]);
                p[r] = dpp_add<ROR8>(p[r]);
            }
            if (lc == 0) {
                int rbase = rt * 16 + lg * 4;      // D row = 4*(lane>>4)+reg
                #pragma unroll
                for (int r = 0; r < 4; ++r) s_sc[rbase + r] = p[r] + b2;
            }
        }
    }
    __syncthreads();

    // ---------------- P2: masked scaled softmax ---------------------------------
    const int len = lens[b];
    float sc = -INFINITY;
    if (tid < HS) sc = ((tid < len) ? s_sc[tid] : -4294967296.0f) * 0.125f;
    float mx = sc;
    mx = dpp_max<ROR1>(mx); mx = dpp_max<ROR2>(mx);
    mx = dpp_max<ROR4>(mx); mx = dpp_max<ROR8>(mx);
    mx = fmaxf(mx, swz_xor16(mx));
    mx = fmaxf(mx, __shfl_xor(mx, 32));
    if ((tid & 63) == 0) s_red[wid] = mx;
    __syncthreads();
    float gmax = s_red[0];
    #pragma unroll
    for (int k = 1; k < 8; ++k) gmax = fmaxf(gmax, s_red[k]);
    float e = 0.f;
    if (tid < HS) { e = __expf(sc - gmax); s_sc[tid] = e; }
    float sm = e;
    sm = dpp_add<ROR1>(sm); sm = dpp_add<ROR2>(sm);
    sm = dpp_add<ROR4>(sm); sm = dpp_add<ROR8>(sm);
    sm += swz_xor16(sm);
    sm += __shfl_xor(sm, 32);
    if ((tid & 63) == 0) s_red[8 + wid] = sm;
    __syncthreads();
    float den = s_red[8];
    #pragma unroll
    for (int k = 9; k < 16; ++k) den += s_red[k];
    const float inv = 1.0f / den;

    // ---------------- P3: weighted sum, pure f32 from global --------------------
    {
        float a3[8] = {0.f, 0.f, 0.f, 0.f, 0.f, 0.f, 0.f, 0.f};
        for (int rb = wid; rb < 25; rb += 8) {     // wave-uniform trip count
            int s = rb * 8 + (lane >> 3);          // <= 199
            const float* rp = hb + s * 64 + (lane & 7) * 8;
            float4 v0 = *(const float4*)rp;
            float4 v1 = *(const float4*)(rp + 4);
            float wgt = s_sc[s];
            a3[0] = fmaf(wgt, v0.x, a3[0]); a3[1] = fmaf(wgt, v0.y, a3[1]);
            a3[2] = fmaf(wgt, v0.z, a3[2]); a3[3] = fmaf(wgt, v0.w, a3[3]);
            a3[4] = fmaf(wgt, v1.x, a3[4]); a3[5] = fmaf(wgt, v1.y, a3[5]);
            a3[6] = fmaf(wgt, v1.z, a3[6]); a3[7] = fmaf(wgt, v1.w, a3[7]);
        }
        #pragma unroll
        for (int j = 0; j < 8; ++j) {              // reduce over lane bits 3,4,5
            float x = dpp_add<ROR8>(a3[j]);
            x += swz_xor16(x);
            x += __shfl_xor(x, 32);
            a3[j] = x;
        }
        if (lane < 8) {
            float* dst = &s_part[wid * 64 + lane * 8];
            *(float4*)dst       = make_float4(a3[0], a3[1], a3[2], a3[3]);
            *(float4*)(dst + 4) = make_float4(a3[4], a3[5], a3[6], a3[7]);
        }
    }
    __syncthreads();
    if (tid < DIMV) {
        float res = 0.f;
        #pragma unroll
        for (int k = 0; k < 8; ++k) res += s_part[k * 64 + tid];
        out[(size_t)b * DIMV + tid] = res * inv;
    }
}

extern "C" void kernel_launch(void* const* d_in, const int* in_sizes, int n_in,
                              void* d_out, int out_size, void* d_ws, size_t ws_size,
                              hipStream_t stream) {
    const float* cand = (const float*)d_in[0];
    const float* hist = (const float*)d_in[1];
    const int*   lens = (const int*)d_in[2];
    const float* W1   = (const float*)d_in[3];
    const float* B1   = (const float*)d_in[4];
    const float* W2   = (const float*)d_in[5];
    const float* B2   = (const float*)d_in[6];
    float* out = (float*)d_out;

    const int B = in_sizes[0] / DIMV;  // 4096
    din_attn_kernel<<<B, NTH, 0, stream>>>(cand, hist, lens, W1, B1, W2, B2, out);
}

// Round 8
// 38.831 us; speedup vs baseline: 1.4930x; 1.4930x over previous
//
#include <hip/hip_runtime.h>
#include <math.h>

#define HS    200   // HIST_SIZE
#define DIMV  64    // DIM
#define HID   32    // HIDDEN
#define NTH   512

typedef __attribute__((ext_vector_type(8))) short short8;   // 8 bf16 (4 VGPRs)
typedef __attribute__((ext_vector_type(4))) float f32x4;    // MFMA acc
typedef __bf16 bf2_t __attribute__((ext_vector_type(2)));
typedef float  f2_t  __attribute__((ext_vector_type(2)));

// packed f32x2 -> bf16x2 (RNE) -> v_cvt_pk_bf16_f32
__device__ __forceinline__ unsigned cvt2(float x, float y) {
    f2_t f = {x, y};
    bf2_t bv = __builtin_convertvector(f, bf2_t);
    union { bf2_t b; unsigned u; } un;
    un.b = bv;
    return un.u;
}
__device__ __forceinline__ float bf16f(short x) {
    return __uint_as_float(((unsigned)(unsigned short)x) << 16);
}

// DPP cross-lane (VALU pipe, no lgkmcnt)
template<int CTRL>
__device__ __forceinline__ float dpp_add(float x) {
    int y = __builtin_amdgcn_update_dpp(0, __float_as_int(x), CTRL, 0xF, 0xF, true);
    return x + __int_as_float(y);
}
template<int CTRL>
__device__ __forceinline__ float dpp_max(float x) {
    int y = __builtin_amdgcn_update_dpp(0, __float_as_int(x), CTRL, 0xF, 0xF, true);
    return fmaxf(x, __int_as_float(y));
}
#define ROR1  0x121
#define ROR2  0x122
#define ROR4  0x124
#define ROR8  0x128
#define QXOR1 0xB1   // quad_perm [1,0,3,2]
#define QXOR2 0x4E   // quad_perm [2,3,0,1]
#define HMIRR 0x141  // row_half_mirror
__device__ __forceinline__ float swz_xor16(float x) {  // lane ^ 16 (within 32)
    return __int_as_float(__builtin_amdgcn_ds_swizzle(__float_as_int(x), 0x401F));
}

// s_h: 208 rows x 64 ushort (128 B/row). 16-B groups XOR-swizzled by (row&7).
// s_Mt: 32 rows x 64 ushort, same swizzle.

__global__ __launch_bounds__(NTH, 8) void din_attn_kernel(
    const float* __restrict__ cand,   // B x 64
    const float* __restrict__ hist,   // B x 200 x 64
    const int*   __restrict__ lens,   // B
    const float* __restrict__ W1,     // 256 x 32
    const float* __restrict__ B1,     // 32
    const float* __restrict__ W2,     // 32
    const float* __restrict__ B2,     // 1
    float* __restrict__ out)          // B x 64
{
    __shared__ __align__(16) unsigned short s_h[208 * 64];   // 26624 B
    __shared__ __align__(16) unsigned char  s_u[4096];       // Mt (P0/P1) | part (P3)
    __shared__ float s_sc[208];         // 832 B
    __shared__ float s_c[HID];          // 128 B
    __shared__ float s_w2[HID];         // 128 B
    __shared__ float s_red[16];         // 64 B   -> 31872 B total (4 blocks/CU)

    unsigned short* s_Mt   = (unsigned short*)s_u;
    float*          s_part = (float*)s_u;            // 8 waves x 64 f = 2 KB

    const int b   = blockIdx.x;
    const int tid = threadIdx.x;
    const int lane = tid & 63, wid = tid >> 6;
    const float* cb = cand + (size_t)b * DIMV;

    const int len  = lens[b];
    const int nrow = (len == 0) ? HS : len;   // rows that matter (len==0: uniform mean)
    const int npairs = nrow * 8;              // b128 stage units (8 per row)

    // ---------------- P0: stage hist rows < nrow (bf16, swizzled); Mt & c -------
    const float4* hp = (const float4*)(hist + (size_t)b * (HS * DIMV));
    float4 va[4], vb[4];
    #pragma unroll
    for (int j = 0; j < 4; ++j) {
        int pi = tid + j * NTH;
        if (pi < npairs) {
            va[j] = hp[2 * pi];
            vb[j] = hp[2 * pi + 1];
        }
    }

    if (tid < 256) {   // Mt[h][f] = bf16(Wb - Wd + cand[f]*Wc), one b128/thread
        const int h = tid & 31, fg = tid >> 5;     // f = fg*8..fg*8+7
        float4 cA = *(const float4*)(cb + fg * 8);
        float4 cB = *(const float4*)(cb + fg * 8 + 4);
        float cf[8] = {cA.x, cA.y, cA.z, cA.w, cB.x, cB.y, cB.z, cB.w};
        float m[8];
        #pragma unroll
        for (int ff = 0; ff < 8; ++ff) {
            int f = fg * 8 + ff;
            m[ff] = W1[(DIMV + f) * HID + h]
                  - W1[(3 * DIMV + f) * HID + h]
                  + cf[ff] * W1[(2 * DIMV + f) * HID + h];
        }
        uint4 mw = make_uint4(cvt2(m[0], m[1]), cvt2(m[2], m[3]),
                              cvt2(m[4], m[5]), cvt2(m[6], m[7]));
        int pg = fg ^ (h & 7);
        *(uint4*)&s_Mt[h * 64 + pg * 8] = mw;
        if (tid < HID) s_w2[tid] = W2[tid];
    } else {           // c[h] = sum_f cand[f]*(Wa+Wd)[f][h] + B1[h], 8-way split
        const int t2 = tid - 256;
        const int h = t2 >> 3, fg = t2 & 7;
        float p = 0.f;
        #pragma unroll
        for (int ff = 0; ff < 8; ++ff) {
            int f = fg * 8 + ff;
            p += cb[f] * (W1[f * HID + h] + W1[(3 * DIMV + f) * HID + h]);
        }
        p = dpp_add<QXOR1>(p);
        p = dpp_add<QXOR2>(p);
        p = dpp_add<HMIRR>(p);
        if ((tid & 7) == 0) s_c[h] = p + B1[h];
    }

    #pragma unroll
    for (int j = 0; j < 4; ++j) {
        int pi = tid + j * NTH;             // pair index; 8 pairs per row
        if (pi < npairs) {
            int r = pi >> 3, g = pi & 7;
            int pg = g ^ (r & 7);
            uint4 w = make_uint4(cvt2(va[j].x, va[j].y), cvt2(va[j].z, va[j].w),
                                 cvt2(vb[j].x, vb[j].y), cvt2(vb[j].z, vb[j].w));
            *(uint4*)&s_h[r * 64 + pg * 8] = w;
        }
    }
    __syncthreads();

    // ---------------- P1: scores via MFMA over ceil(len/16) tiles ---------------
    {
        const int nt = (len + 15) >> 4;            // 0 when len==0 -> skip
        const int lc = lane & 15, lg = lane >> 4;
        const float c0  = s_c[lc],  c1  = s_c[16 + lc];
        const float w20 = s_w2[lc], w21 = s_w2[16 + lc];
        const float b2  = B2[0];

        short8 b00 = *(const short8*)&s_Mt[lc * 64        + ((lg)     ^ (lc & 7)) * 8];
        short8 b01 = *(const short8*)&s_Mt[lc * 64        + ((4 + lg) ^ (lc & 7)) * 8];
        short8 b10 = *(const short8*)&s_Mt[(16 + lc) * 64 + ((lg)     ^ (lc & 7)) * 8];
        short8 b11 = *(const short8*)&s_Mt[(16 + lc) * 64 + ((4 + lg) ^ (lc & 7)) * 8];

        for (int rt = wid; rt < nt; rt += 8) {     // block-uniform trip count
            int s = rt * 16 + lc;
            s = (s < len) ? s : (len - 1);         // clamp: only staged rows
            short8 a0 = *(const short8*)&s_h[s * 64 + ((lg)     ^ (s & 7)) * 8];
            short8 a1 = *(const short8*)&s_h[s * 64 + ((4 + lg) ^ (s & 7)) * 8];
            f32x4 acc0 = {c0, c0, c0, c0};         // fold +c into accumulator
            acc0 = __builtin_amdgcn_mfma_f32_16x16x32_bf16(a0, b00, acc0, 0, 0, 0);
            acc0 = __builtin_amdgcn_mfma_f32_16x16x32_bf16(a1, b01, acc0, 0, 0, 0);
            f32x4 acc1 = {c1, c1, c1, c1};
            acc1 = __builtin_amdgcn_mfma_f32_16x16x32_bf16(a0, b10, acc1, 0, 0, 0);
            acc1 = __builtin_amdgcn_mfma_f32_16x16x32_bf16(a1, b11, acc1, 0, 0, 0);
            float p[4];
            #pragma unroll
            for (int r = 0; r < 4; ++r)
                p[r] = fmaxf(acc0[r], 0.f) * w20 + fmaxf(acc1[r], 0.f) * w21;
            #pragma unroll
            for (int r = 0; r < 4; ++r) {          // 16-lane rotate-reduce, VALU pipe
                p[r] = dpp_add<ROR1>(p[r]);
                p[r] = dpp_add<ROR2>(p[r]);
                p[r] = dpp_add<ROR4>(p[r]);
                p[r] = dpp_add<ROR8>(p[r]);
            }
            if (lc == 0) {
                int rbase = rt * 16 + lg * 4;      // D row = 4*(lane>>4)+reg
                #pragma unroll
                for (int r = 0; r < 4; ++r) s_sc[rbase + r] = p[r] + b2;
            }
        }
    }
    __syncthreads();

    // ---------------- P2: masked scaled softmax ---------------------------------
    float sc = -INFINITY;
    if (tid < HS) {
        sc = ((tid < len) ? s_sc[tid] : -4294967296.0f) * 0.125f;
        if (len == 0) sc = 0.f;                    // uniform weights -> mean
    }
    float mx = sc;
    mx = dpp_max<ROR1>(mx); mx = dpp_max<ROR2>(mx);
    mx = dpp_max<ROR4>(mx); mx = dpp_max<ROR8>(mx);
    mx = fmaxf(mx, swz_xor16(mx));
    mx = fmaxf(mx, __shfl_xor(mx, 32));
    if ((tid & 63) == 0) s_red[wid] = mx;
    __syncthreads();
    float gmax = s_red[0];
    #pragma unroll
    for (int k = 1; k < 8; ++k) gmax = fmaxf(gmax, s_red[k]);
    float e = 0.f;
    if (tid < HS) { e = __expf(sc - gmax); s_sc[tid] = e; }
    float sm = e;
    sm = dpp_add<ROR1>(sm); sm = dpp_add<ROR2>(sm);
    sm = dpp_add<ROR4>(sm); sm = dpp_add<ROR8>(sm);
    sm += swz_xor16(sm);
    sm += __shfl_xor(sm, 32);
    if ((tid & 63) == 0) s_red[8 + wid] = sm;
    __syncthreads();
    float den = s_red[8];
    #pragma unroll
    for (int k = 9; k < 16; ++k) den += s_red[k];
    const float inv = 1.0f / den;

    // ---------------- P3: weighted sum over nrow rows (b128 LDS reads) ----------
    {
        const int nrb = (nrow + 7) >> 3;           // block-uniform
        float a3[8] = {0.f, 0.f, 0.f, 0.f, 0.f, 0.f, 0.f, 0.f};
        for (int rb = wid; rb < nrb; rb += 8) {
            int s = rb * 8 + (lane >> 3);
            float wgt = (s < nrow) ? s_sc[s] : 0.f;
            s = (s < nrow) ? s : (nrow - 1);       // clamp: only staged rows
            int g = lane & 7;                      // d-range g*8..g*8+7
            short8 hv = *(const short8*)&s_h[s * 64 + (g ^ (s & 7)) * 8];
            #pragma unroll
            for (int j = 0; j < 8; ++j) a3[j] = fmaf(wgt, bf16f(hv[j]), a3[j]);
        }
        #pragma unroll
        for (int j = 0; j < 8; ++j) {              // reduce over lane bits 3,4,5
            float x = dpp_add<ROR8>(a3[j]);
            x += swz_xor16(x);
            x += __shfl_xor(x, 32);
            a3[j] = x;
        }
        if (lane < 8) {
            float* dst = &s_part[wid * 64 + lane * 8];
            *(float4*)dst       = make_float4(a3[0], a3[1], a3[2], a3[3]);
            *(float4*)(dst + 4) = make_float4(a3[4], a3[5], a3[6], a3[7]);
        }
    }
    __syncthreads();
    if (tid < DIMV) {
        float res = 0.f;
        #pragma unroll
        for (int k = 0; k < 8; ++k) res += s_part[k * 64 + tid];
        out[(size_t)b * DIMV + tid] = res * inv;
    }
}

extern "C" void kernel_launch(void* const* d_in, const int* in_sizes, int n_in,
                              void* d_out, int out_size, void* d_ws, size_t ws_size,
                              hipStream_t stream) {
    const float* cand = (const float*)d_in[0];
    const float* hist = (const float*)d_in[1];
    const int*   lens = (const int*)d_in[2];
    const float* W1   = (const float*)d_in[3];
    const float* B1   = (const float*)d_in[4];
    const float* W2   = (const float*)d_in[5];
    const float* B2   = (const float*)d_in[6];
    float* out = (float*)d_out;

    const int B = in_sizes[0] / DIMV;  // 4096
    din_attn_kernel<<<B, NTH, 0, stream>>>(cand, hist, lens, W1, B1, W2, B2, out);
}